// Round 19
// baseline (108.363 us; speedup 1.0000x reference)
//
#include <hip/hip_runtime.h>
#include <math.h>

#define LL 2048
#define HH 256
#define BB 8
#define NN 64
#define HN (HH*NN)       // 16384
#define ELEMS (BB*HH*LL) // 4194304

typedef __attribute__((ext_vector_type(8))) short bf16x8v;
typedef __attribute__((ext_vector_type(4))) float f32x4v;

static inline __device__ ushort f2b_rne(float f) {
  uint u = __float_as_uint(f);
  return (ushort)((u + 0x7fffu + ((u >> 16) & 1u)) >> 16);
}
static inline __device__ float b2f(ushort u) { return __uint_as_float((uint)u << 16); }
#define UNPK(u, lo, hi) { lo = __uint_as_float((u)<<16); hi = __uint_as_float((u)&0xffff0000u); }

// ---------------- init: tt (blk<8) | W->bf16 (blk<200) | per-h prep (blk>=200) ----------
__global__ __launch_bounds__(256) void init_kernel(
    const float* __restrict__ t, const float* __restrict__ W_t, const float* __restrict__ b_t,
    const float* __restrict__ log_dt, const float* __restrict__ log_A_real,
    const float* __restrict__ A_imag,
    const float* __restrict__ B_re, const float* __restrict__ B_im,
    const float* __restrict__ C_re, const float* __restrict__ C_im,
    const float* __restrict__ Dp,
    const float* __restrict__ Wo, const float* __restrict__ W1, const float* __restrict__ W2,
    float* __restrict__ P, float* __restrict__ tt,
    ushort* __restrict__ Wob, ushort* __restrict__ W1b, ushort* __restrict__ W2b,
    ushort* __restrict__ Mc, ushort* __restrict__ Vc, ushort* __restrict__ Uc,
    float* __restrict__ rT) {
  int blk = blockIdx.x;
  int tid = threadIdx.x;
  if (blk < BB) {
    int b = blk, h = tid;
    float s = b_t[h];
    const float* trow = t + b*HH;
    const float* wrow = W_t + h*HH;
    for (int c = 0; c < HH; ++c) s = fmaf(trow[c], wrow[c], s);
    tt[b*HH + h] = s;
    return;
  }
  if (blk < BB + 192) {
    int q = blk - BB;
    int m = q >> 6;
    int i = (q & 63)*1024 + tid*4;
    const float* src = (m==0) ? Wo : (m==1 ? W1 : W2);
    ushort* dst = (m==0) ? Wob : (m==1 ? W1b : W2b);
    float4 v = *reinterpret_cast<const float4*>(src + i);
    union { ushort us[4]; uint2 u2; } pk;
    pk.us[0] = f2b_rne(v.x); pk.us[1] = f2b_rne(v.y);
    pk.us[2] = f2b_rne(v.z); pk.us[3] = f2b_rne(v.w);
    *reinterpret_cast<uint2*>(dst + i) = pk.u2;
    return;
  }
  int h = blk - (BB + 192);
  __shared__ float RRe[65][64], RIm[65][64];
  __shared__ float K0[64], K1[64];
  __shared__ float W0r[64], W0i[64], W1r[64], W1i[64];
  float dt = expf(log_dt[h]);
  for (int idx = tid; idx < 65*64; idx += 256) {
    int d = idx >> 6, n = idx & 63;
    float are = -expf(log_A_real[h*64+n]);
    float aim = A_imag[h*64+n];
    float ang = dt*aim*(float)d;
    float mag = expf(dt*are*(float)d);
    RRe[d][n] = mag * cosf(ang);
    RIm[d][n] = mag * sinf(ang);
  }
  __syncthreads();
  if (tid < 64) {
    int n = tid, gid = h*64 + n;
    float are = -expf(log_A_real[gid]);
    float aim = A_imag[gid];
    float rre = RRe[1][n], rim = RIm[1][n];
    float inv  = 1.0f / (are*are + aim*aim);
    float m_re = rre - 1.0f, m_im = rim;
    float q_re = (m_re*are + m_im*aim) * inv;
    float q_im = (m_im*are - m_re*aim) * inv;
    float bre = B_re[gid], bim = B_im[gid];
    float db_re = q_re*bre - q_im*bim;
    float db_im = q_re*bim + q_im*bre;
    float c0r = C_re[gid],      c0i = C_im[gid];
    float c1r = C_re[HN + gid], c1i = C_im[HN + gid];
    float w0r = 2.0f*(c0r*db_re - c0i*db_im), w0i = 2.0f*(c0r*db_im + c0i*db_re);
    float w1r = 2.0f*(c1r*db_re - c1i*db_im), w1i = 2.0f*(c1r*db_im + c1i*db_re);
    W0r[n] = w0r; W0i[n] = w0i; W1r[n] = w1r; W1i[n] = w1i;
    P[gid]        = w0r;
    P[HN + gid]   = w0i;
    P[2*HN + gid] = w1r;
    P[3*HN + gid] = w1i;
    rT[gid*2]   = RRe[64][n];
    rT[gid*2+1] = RIm[64][n];
  }
  __syncthreads();
  if (tid < 128) {
    int d = tid & 63; bool c1 = tid >= 64;
    float s = 0.f;
    if (!c1) for (int n = 0; n < 64; ++n) s += W0r[n]*RRe[d][n] - W0i[n]*RIm[d][n];
    else     for (int n = 0; n < 64; ++n) s += W1r[n]*RRe[d][n] - W1i[n]*RIm[d][n];
    if (c1) K1[d] = s; else K0[d] = s;
  }
  __syncthreads();
  float dh = Dp[h];
  for (int idx = tid; idx < 4096; idx += 256) {
    int i = idx >> 6, j = idx & 63;
    float v = (i > j) ? K0[i-j] : (i < j ? K1[j-i-1] : (K0[0] + dh));
    Mc[(size_t)h*4096 + idx] = f2b_rne(v);
  }
  for (int idx = tid; idx < 256*64; idx += 256) {
    int row = idx >> 6, j = idx & 63;
    int n = (row >> 1) & 63;
    bool im = row & 1, bwd = row >= 128;
    int d = bwd ? j : 63-j;
    Vc[(size_t)h*16384 + idx] = f2b_rne(im ? RIm[d][n] : RRe[d][n]);
  }
  for (int idx = tid; idx < 64*256; idx += 256) {
    int i = idx >> 8, col = idx & 255;
    int n = (col >> 1) & 63;
    bool im = col & 1, bwd = col >= 128;
    int d = bwd ? 63-i : i+1;
    Uc[(size_t)h*16384 + idx] = f2b_rne(im ? -RIm[d][n] : RRe[d][n]);
  }
}

// ---------------- lnz v2: float4 x loads; one-pass LN -> zb + xt (bf16) ----------------
__global__ __launch_bounds__(256) void lnz_kernel(
    const float* __restrict__ x, const float* __restrict__ tt,
    const float* __restrict__ ln_g, const float* __restrict__ ln_b,
    ushort* __restrict__ zb, ushort* __restrict__ xt) {
  int b  = blockIdx.x >> 6;
  int l0 = (blockIdx.x & 63) * 32;
  int tid = threadIdx.x;
  int r8 = tid >> 3;
  int c  = tid & 7;
  __shared__ ushort XS[256][36];
  __shared__ float SS[32][33], SS2[32][33];
  __shared__ float MU[32], RS[32];
  float s[4] = {0.f,0.f,0.f,0.f}, s2[4] = {0.f,0.f,0.f,0.f};
  #pragma unroll
  for (int it = 0; it < 8; ++it) {
    int h = it*32 + r8;
    float ttv = tt[b*HH + h];
    float vv[4];
    *reinterpret_cast<float4*>(vv) =
        *reinterpret_cast<const float4*>(x + (size_t)(b*HH + h)*LL + l0 + c*4);
    #pragma unroll
    for (int j = 0; j < 4; ++j) {
      float w = vv[j] + ttv;
      s[j] += w; s2[j] = fmaf(w, w, s2[j]);
      XS[h][c*4 + j] = f2b_rne(w);
    }
  }
  #pragma unroll
  for (int j = 0; j < 4; ++j) { SS[c*4+j][r8] = s[j]; SS2[c*4+j][r8] = s2[j]; }
  __syncthreads();
  if (tid < 32) {
    float a = 0.f, a2 = 0.f;
    #pragma unroll
    for (int p = 0; p < 32; ++p) { a += SS[tid][p]; a2 += SS2[tid][p]; }
    float m = a * (1.0f/HH);
    float var = a2 * (1.0f/HH) - m*m;
    MU[tid] = m;
    RS[tid] = 1.0f / sqrtf(var + 1e-5f);
  }
  __syncthreads();
  #pragma unroll
  for (int it = 0; it < 8; ++it) {
    int h = it*32 + r8;
    float gg = ln_g[h], bb2 = ln_b[h];
    uint2 u2 = *reinterpret_cast<const uint2*>(&XS[h][c*4]);
    float v0, v1, v2, v3;
    UNPK(u2.x, v0, v1); UNPK(u2.y, v2, v3);
    int l = c*4;
    float z0 = (v0 - MU[l])   * RS[l]   * gg + bb2;
    float z1 = (v1 - MU[l+1]) * RS[l+1] * gg + bb2;
    float z2 = (v2 - MU[l+2]) * RS[l+2] * gg + bb2;
    float z3 = (v3 - MU[l+3]) * RS[l+3] * gg + bb2;
    uint2 zo;
    zo.x = (uint)f2b_rne(z0) | ((uint)f2b_rne(z1) << 16);
    zo.y = (uint)f2b_rne(z2) | ((uint)f2b_rne(z3) << 16);
    size_t off = (size_t)(b*HH + h)*LL + l0 + l;
    *reinterpret_cast<uint2*>(zb + off) = zo;
    *reinterpret_cast<uint2*>(xt + off) = u2;
  }
}

// ---------------- ssm_all v2: split over b (4 b's per block) -> 2 blocks/CU ------------
__global__ __launch_bounds__(512) void ssm_all(
    const ushort* __restrict__ zb, const ushort* __restrict__ Vc,
    const ushort* __restrict__ Mc, const ushort* __restrict__ Uc,
    const float* __restrict__ P, const float* __restrict__ rT,
    ushort* __restrict__ g) {
  int b0 = blockIdx.x * 4;
  int h  = blockIdx.y;
  int tid = threadIdx.x, wid = tid >> 6, lane = tid & 63;
  int row16 = lane & 15, kg = lane >> 4;
  __shared__ ushort G[128][260];

  {
    int comp0 = (wid >> 1)*64, bct = (wid & 1)*64;
    f32x4v acc[4][4];
    #pragma unroll
    for (int fm = 0; fm < 4; ++fm)
      #pragma unroll
      for (int fn = 0; fn < 4; ++fn) acc[fm][fn] = (f32x4v){0.f,0.f,0.f,0.f};
    #pragma unroll
    for (int k0 = 0; k0 < 64; k0 += 32) {
      bf16x8v a[4], bv[4];
      #pragma unroll
      for (int fm = 0; fm < 4; ++fm)
        a[fm] = *reinterpret_cast<const bf16x8v*>(
            Vc + (size_t)h*16384 + (comp0 + fm*16 + row16)*64 + k0 + kg*8);
      #pragma unroll
      for (int fn = 0; fn < 4; ++fn) {
        int bc = bct + fn*16 + row16; int b = b0 + (bc >> 5), c = bc & 31;
        bv[fn] = *reinterpret_cast<const bf16x8v*>(
            zb + ((size_t)(b*HH + h))*LL + c*64 + k0 + kg*8);
      }
      #pragma unroll
      for (int fm = 0; fm < 4; ++fm)
        #pragma unroll
        for (int fn = 0; fn < 4; ++fn)
          acc[fm][fn] = __builtin_amdgcn_mfma_f32_16x16x32_bf16(a[fm], bv[fn], acc[fm][fn], 0,0,0);
    }
    #pragma unroll
    for (int fm = 0; fm < 4; ++fm)
      #pragma unroll
      for (int fn = 0; fn < 4; ++fn) {
        int bc = bct + fn*16 + row16;
        int comp = comp0 + fm*16 + kg*4;
        union { ushort us[4]; uint2 u2; } pk;
        #pragma unroll
        for (int r = 0; r < 4; ++r) pk.us[r] = f2b_rne(acc[fm][fn][r]);
        *reinterpret_cast<uint2*>(&G[bc][comp]) = pk.u2;
      }
  }
  __syncthreads();

  {
    int bloc = wid & 3, dir = wid >> 2;
    int n = lane;
    float w_re = dir ? P[2*HN + h*64+n] : P[h*64+n];
    float w_im = dir ? P[3*HN + h*64+n] : P[HN + h*64+n];
    float rtr = rT[(h*64+n)*2], rti = rT[(h*64+n)*2+1];
    float sre = 0.f, sim = 0.f;
    if (dir == 0) {
      for (int c = 0; c < 32; ++c) {
        uint* slot = reinterpret_cast<uint*>(&G[bloc*32 + c][2*n]);
        uint gg = *slot;
        float ure = w_re*sre - w_im*sim;
        float uim = w_re*sim + w_im*sre;
        *slot = (uint)f2b_rne(ure) | ((uint)f2b_rne(uim) << 16);
        float gre, gim; UNPK(gg, gre, gim);
        float nre = rtr*sre - rti*sim + gre;
        float nim = rtr*sim + rti*sre + gim;
        sre = nre; sim = nim;
      }
    } else {
      for (int c = 31; c >= 0; --c) {
        uint* slot = reinterpret_cast<uint*>(&G[bloc*32 + c][128 + 2*n]);
        uint gg = *slot;
        float ure = w_re*sre - w_im*sim;
        float uim = w_re*sim + w_im*sre;
        *slot = (uint)f2b_rne(ure) | ((uint)f2b_rne(uim) << 16);
        float gre, gim; UNPK(gg, gre, gim);
        float nre = rtr*sre - rti*sim + gre;
        float nim = rtr*sim + rti*sre + gim;
        sre = nre; sim = nim;
      }
    }
  }
  __syncthreads();

  {
    int i0 = (wid & 3)*16, bct = (wid >> 2)*64;
    f32x4v acc[4];
    #pragma unroll
    for (int fn = 0; fn < 4; ++fn) acc[fn] = (f32x4v){0.f,0.f,0.f,0.f};
    #pragma unroll
    for (int k0 = 0; k0 < 64; k0 += 32) {
      bf16x8v a = *reinterpret_cast<const bf16x8v*>(
          Mc + (size_t)h*4096 + (i0 + row16)*64 + k0 + kg*8);
      #pragma unroll
      for (int fn = 0; fn < 4; ++fn) {
        int bc = bct + fn*16 + row16; int b = b0 + (bc >> 5), c = bc & 31;
        bf16x8v bv = *reinterpret_cast<const bf16x8v*>(
            zb + ((size_t)(b*HH + h))*LL + c*64 + k0 + kg*8);
        acc[fn] = __builtin_amdgcn_mfma_f32_16x16x32_bf16(a, bv, acc[fn], 0,0,0);
      }
    }
    #pragma unroll
    for (int k0 = 0; k0 < 256; k0 += 32) {
      bf16x8v a = *reinterpret_cast<const bf16x8v*>(
          Uc + (size_t)h*16384 + (i0 + row16)*256 + k0 + kg*8);
      #pragma unroll
      for (int fn = 0; fn < 4; ++fn) {
        bf16x8v bv = *reinterpret_cast<const bf16x8v*>(&G[bct + fn*16 + row16][k0 + kg*8]);
        acc[fn] = __builtin_amdgcn_mfma_f32_16x16x32_bf16(a, bv, acc[fn], 0,0,0);
      }
    }
    #pragma unroll
    for (int fn = 0; fn < 4; ++fn) {
      int bc = bct + fn*16 + row16; int b = b0 + (bc >> 5), c = bc & 31;
      union { ushort us[4]; uint2 u2; } pk;
      #pragma unroll
      for (int r = 0; r < 4; ++r) {
        float v = acc[fn][r];
        float ge = 0.5f * v * (1.0f + erff(v * 0.70710678118654752f));
        pk.us[r] = f2b_rne(ge);
      }
      *reinterpret_cast<uint2*>(&g[((size_t)(b*HH + h))*LL + c*64 + i0 + kg*4]) = pk.u2;
    }
  }
}

// ---------------- gate_k: phase A only -> gate bf16 [b][l][o] (contiguous rows) --------
__global__ __launch_bounds__(256, 2) void gate_k(
    const ushort* __restrict__ g, const ushort* __restrict__ Wob,
    const float* __restrict__ b_out, const ushort* __restrict__ xt,
    ushort* __restrict__ gate) {
  int l0 = blockIdx.x * 32;
  int b  = blockIdx.y;
  int tid = threadIdx.x, wid = tid >> 6, lane = tid & 63;
  int row16 = lane & 15, kg = lane >> 4;
  int o0 = wid * 64;

  __shared__ ushort Tg[32][274];
  __shared__ ushort X[256][38];

  bf16x8v wA[8][4];
  #pragma unroll
  for (int k8 = 0; k8 < 8; ++k8)
    #pragma unroll
    for (int fo = 0; fo < 4; ++fo)
      wA[k8][fo] = *reinterpret_cast<const bf16x8v*>(
          Wob + (size_t)(o0 + fo*16 + row16)*HH + k8*32 + kg*8);

  {
    const ushort* gsrc = g + (size_t)b*HH*LL + l0;
    int cq = tid & 7;
    #pragma unroll
    for (int p = 0; p < 8; ++p) {
      int h = p*32 + (tid >> 3);
      uint2 v = *reinterpret_cast<const uint2*>(gsrc + (size_t)h*LL + cq*4);
      union { uint2 u2; ushort us[4]; } pk; pk.u2 = v;
      #pragma unroll
      for (int j = 0; j < 4; ++j) Tg[cq*4 + j][h] = pk.us[j];
    }
    const ushort* xsrc = xt + (size_t)b*HH*LL + l0;
    #pragma unroll
    for (int p = 0; p < 8; ++p) {
      int o = p*32 + (tid >> 3);
      uint2 v = *reinterpret_cast<const uint2*>(xsrc + (size_t)o*LL + cq*4);
      *reinterpret_cast<uint2*>(&X[o][cq*4]) = v;
    }
  }
  float biasA[4][4];
  #pragma unroll
  for (int fo = 0; fo < 4; ++fo)
    #pragma unroll
    for (int r = 0; r < 4; ++r)
      biasA[fo][r] = b_out[o0 + fo*16 + kg*4 + r];
  __syncthreads();

  f32x4v accA[4][2];
  #pragma unroll
  for (int fo = 0; fo < 4; ++fo)
    #pragma unroll
    for (int fl = 0; fl < 2; ++fl) accA[fo][fl] = (f32x4v){0.f,0.f,0.f,0.f};
  #pragma unroll
  for (int k8 = 0; k8 < 8; ++k8) {
    bf16x8v bb[2];
    #pragma unroll
    for (int fl = 0; fl < 2; ++fl)
      bb[fl] = *reinterpret_cast<const bf16x8v*>(&Tg[fl*16+row16][k8*32 + kg*8]);
    #pragma unroll
    for (int fo = 0; fo < 4; ++fo)
      #pragma unroll
      for (int fl = 0; fl < 2; ++fl)
        accA[fo][fl] = __builtin_amdgcn_mfma_f32_16x16x32_bf16(wA[k8][fo], bb[fl], accA[fo][fl], 0,0,0);
  }
  #pragma unroll
  for (int fo = 0; fo < 4; ++fo)
    #pragma unroll
    for (int fl = 0; fl < 2; ++fl) {
      union { ushort us[4]; uint2 u2; } pk;
      int l = fl*16 + row16;
      #pragma unroll
      for (int r = 0; r < 4; ++r) {
        int o = o0 + fo*16 + kg*4 + r;
        float v = accA[fo][fl][r] + biasA[fo][r] + b2f(X[o][l]);
        float gt = tanhf(v) * (1.0f/(1.0f + expf(-v)));
        pk.us[r] = f2b_rne(gt);
      }
      *reinterpret_cast<uint2*>(&gate[((size_t)b*LL + l0 + l)*HH + o0 + fo*16 + kg*4]) = pk.u2;
    }
}

// ---------------- out_k: W1/W2 GEMMs, l-range 512/block, contiguous stores -------------
// grid (4, 8, 8) = (lr, ot, b); 256 th = 4 waves, wave owns 128-l range; no LDS.
__global__ __launch_bounds__(256) void out_k(
    const ushort* __restrict__ gate, const ushort* __restrict__ W1b,
    const ushort* __restrict__ W2b,
    const float* __restrict__ b1v, const float* __restrict__ b2v,
    const ushort* __restrict__ xt, const float* __restrict__ tt,
    float* __restrict__ out1, float* __restrict__ out2) {
  int lr = blockIdx.x, ot = blockIdx.y, b = blockIdx.z;
  int tid = threadIdx.x, wid = tid >> 6, lane = tid & 63;
  int row16 = lane & 15, kg = lane >> 4;
  int lbase = lr*512 + wid*128;
  int o0 = ot*32;

  f32x4v a1[2][8], a2[2][8];   // [fo][lf]
  #pragma unroll
  for (int fo = 0; fo < 2; ++fo)
    #pragma unroll
    for (int lf = 0; lf < 8; ++lf) { a1[fo][lf] = (f32x4v){0.f,0.f,0.f,0.f}; a2[fo][lf] = a1[fo][lf]; }

  for (int k0 = 0; k0 < HH; k0 += 32) {
    bf16x8v w1f[2], w2f[2];
    #pragma unroll
    for (int fo = 0; fo < 2; ++fo) {
      w1f[fo] = *reinterpret_cast<const bf16x8v*>(W1b + (size_t)(o0+fo*16+row16)*HH + k0 + kg*8);
      w2f[fo] = *reinterpret_cast<const bf16x8v*>(W2b + (size_t)(o0+fo*16+row16)*HH + k0 + kg*8);
    }
    #pragma unroll
    for (int lf = 0; lf < 8; ++lf) {
      bf16x8v gf = *reinterpret_cast<const bf16x8v*>(
          gate + ((size_t)b*LL + lbase + lf*16 + row16)*HH + k0 + kg*8);
      #pragma unroll
      for (int fo = 0; fo < 2; ++fo) {
        a1[fo][lf] = __builtin_amdgcn_mfma_f32_16x16x32_bf16(gf, w1f[fo], a1[fo][lf], 0,0,0);
        a2[fo][lf] = __builtin_amdgcn_mfma_f32_16x16x32_bf16(gf, w2f[fo], a2[fo][lf], 0,0,0);
      }
    }
  }

  #pragma unroll
  for (int fo = 0; fo < 2; ++fo) {
    int o = o0 + fo*16 + row16;
    float bias1 = b1v[o] - tt[b*HH + o];
    float bias2 = b2v[o];
    #pragma unroll
    for (int lf = 0; lf < 8; ++lf) {
      int l = lbase + lf*16 + kg*4;
      size_t off = ((size_t)(b*HH + o))*LL + l;
      uint2 xv = *reinterpret_cast<const uint2*>(xt + off);
      float x0, x1, x2, x3;
      UNPK(xv.x, x0, x1); UNPK(xv.y, x2, x3);
      float4 v1;
      v1.x = a1[fo][lf][0] + bias1 + x0;
      v1.y = a1[fo][lf][1] + bias1 + x1;
      v1.z = a1[fo][lf][2] + bias1 + x2;
      v1.w = a1[fo][lf][3] + bias1 + x3;
      *reinterpret_cast<float4*>(&out1[off]) = v1;
      float4 v2;
      v2.x = a2[fo][lf][0] + bias2;
      v2.y = a2[fo][lf][1] + bias2;
      v2.z = a2[fo][lf][2] + bias2;
      v2.w = a2[fo][lf][3] + bias2;
      *reinterpret_cast<float4*>(&out2[off]) = v2;
    }
  }
}

extern "C" void kernel_launch(void* const* d_in, const int* in_sizes, int n_in,
                              void* d_out, int out_size, void* d_ws, size_t ws_size,
                              hipStream_t stream) {
  const float* x    = (const float*)d_in[0];
  const float* t    = (const float*)d_in[1];
  const float* W_t  = (const float*)d_in[2];
  const float* b_t  = (const float*)d_in[3];
  const float* ln_g = (const float*)d_in[4];
  const float* ln_b = (const float*)d_in[5];
  const float* log_dt = (const float*)d_in[6];
  const float* log_A_real = (const float*)d_in[7];
  const float* A_imag = (const float*)d_in[8];
  const float* B_re = (const float*)d_in[9];
  const float* B_im = (const float*)d_in[10];
  const float* C_re = (const float*)d_in[11];
  const float* C_im = (const float*)d_in[12];
  const float* Dp   = (const float*)d_in[13];
  const float* W_out= (const float*)d_in[14];
  const float* b_out= (const float*)d_in[15];
  const float* W1   = (const float*)d_in[16];
  const float* b1   = (const float*)d_in[17];
  const float* W2   = (const float*)d_in[18];
  const float* b2   = (const float*)d_in[19];

  float* out1 = (float*)d_out;
  float* out2 = out1 + ELEMS;

  // ws: P(4HN) | tt | rT(2HN) | zb | Mc | Vc | Uc | g | Wob | W1b | W2b | xt
  float* P    = (float*)d_ws;
  float* tt   = P + 4*HN;
  float* rT   = tt + BB*HH;
  ushort* zb  = (ushort*)(rT + 2*HN);
  ushort* Mc  = zb + ELEMS;
  ushort* Vc  = Mc + (size_t)4096*HH;
  ushort* Uc  = Vc + (size_t)16384*HH;
  ushort* g   = Uc + (size_t)16384*HH;
  ushort* Wob = g + ELEMS;
  ushort* W1b = Wob + HH*HH;
  ushort* W2b = W1b + HH*HH;
  ushort* xt  = W2b + HH*HH;
  ushort* gate = zb;   // zb region (8MB) dead after ssm_all; gate = [b][l][o] bf16 (8MB)

  init_kernel<<<BB + 192 + HH, 256, 0, stream>>>(
      t, W_t, b_t, log_dt, log_A_real, A_imag, B_re, B_im, C_re, C_im, Dp,
      W_out, W1, W2, P, tt, Wob, W1b, W2b, Mc, Vc, Uc, rT);
  lnz_kernel<<<BB*64, 256, 0, stream>>>(x, tt, ln_g, ln_b, zb, xt);
  ssm_all<<<dim3(2, HH), 512, 0, stream>>>(zb, Vc, Mc, Uc, P, rT, g);
  gate_k<<<dim3(LL/32, BB), 256, 0, stream>>>(g, Wob, b_out, xt, gate);
  out_k<<<dim3(4, 8, BB), 256, 0, stream>>>(gate, W1b, W2b, b1, b2, xt, tt, out1, out2);
}

// Round 20
// 101.735 us; speedup vs baseline: 1.0652x; 1.0652x over previous
//
#include <hip/hip_runtime.h>
#include <math.h>

#define LL 2048
#define HH 256
#define BB 8
#define NN 64
#define HN (HH*NN)       // 16384
#define ELEMS (BB*HH*LL) // 4194304

typedef __attribute__((ext_vector_type(8))) short bf16x8v;
typedef __attribute__((ext_vector_type(4))) float f32x4v;

static inline __device__ ushort f2b_rne(float f) {
  uint u = __float_as_uint(f);
  return (ushort)((u + 0x7fffu + ((u >> 16) & 1u)) >> 16);
}
static inline __device__ float b2f(ushort u) { return __uint_as_float((uint)u << 16); }
#define UNPK(u, lo, hi) { lo = __uint_as_float((u)<<16); hi = __uint_as_float((u)&0xffff0000u); }

// ---------------- init: tt (blk<8) | W->bf16 (blk<200) | per-h prep (blk>=200) ----------
// P layout (4*HN floats): w0re | w0im | w1re | w1im
__global__ __launch_bounds__(256) void init_kernel(
    const float* __restrict__ t, const float* __restrict__ W_t, const float* __restrict__ b_t,
    const float* __restrict__ log_dt, const float* __restrict__ log_A_real,
    const float* __restrict__ A_imag,
    const float* __restrict__ B_re, const float* __restrict__ B_im,
    const float* __restrict__ C_re, const float* __restrict__ C_im,
    const float* __restrict__ Dp,
    const float* __restrict__ Wo, const float* __restrict__ W1, const float* __restrict__ W2,
    float* __restrict__ P, float* __restrict__ tt,
    ushort* __restrict__ Wob, ushort* __restrict__ W1b, ushort* __restrict__ W2b,
    ushort* __restrict__ Mc, ushort* __restrict__ Vc, ushort* __restrict__ Uc,
    float* __restrict__ rT) {
  int blk = blockIdx.x;
  int tid = threadIdx.x;
  if (blk < BB) {
    int b = blk, h = tid;
    float s = b_t[h];
    const float* trow = t + b*HH;
    const float* wrow = W_t + h*HH;
    for (int c = 0; c < HH; ++c) s = fmaf(trow[c], wrow[c], s);
    tt[b*HH + h] = s;
    return;
  }
  if (blk < BB + 192) {
    int q = blk - BB;
    int m = q >> 6;
    int i = (q & 63)*1024 + tid*4;
    const float* src = (m==0) ? Wo : (m==1 ? W1 : W2);
    ushort* dst = (m==0) ? Wob : (m==1 ? W1b : W2b);
    float4 v = *reinterpret_cast<const float4*>(src + i);
    union { ushort us[4]; uint2 u2; } pk;
    pk.us[0] = f2b_rne(v.x); pk.us[1] = f2b_rne(v.y);
    pk.us[2] = f2b_rne(v.z); pk.us[3] = f2b_rne(v.w);
    *reinterpret_cast<uint2*>(dst + i) = pk.u2;
    return;
  }
  // ---- prep role: h = blk - 200 ----
  int h = blk - (BB + 192);
  __shared__ float RRe[65][64], RIm[65][64];
  __shared__ float K0[64], K1[64];
  __shared__ float W0r[64], W0i[64], W1r[64], W1i[64];
  float dt = expf(log_dt[h]);
  for (int idx = tid; idx < 65*64; idx += 256) {
    int d = idx >> 6, n = idx & 63;
    float are = -expf(log_A_real[h*64+n]);
    float aim = A_imag[h*64+n];
    float ang = dt*aim*(float)d;
    float mag = expf(dt*are*(float)d);
    RRe[d][n] = mag * cosf(ang);
    RIm[d][n] = mag * sinf(ang);
  }
  __syncthreads();
  if (tid < 64) {
    int n = tid, gid = h*64 + n;
    float are = -expf(log_A_real[gid]);
    float aim = A_imag[gid];
    float rre = RRe[1][n], rim = RIm[1][n];
    float inv  = 1.0f / (are*are + aim*aim);
    float m_re = rre - 1.0f, m_im = rim;
    float q_re = (m_re*are + m_im*aim) * inv;
    float q_im = (m_im*are - m_re*aim) * inv;
    float bre = B_re[gid], bim = B_im[gid];
    float db_re = q_re*bre - q_im*bim;
    float db_im = q_re*bim + q_im*bre;
    float c0r = C_re[gid],      c0i = C_im[gid];
    float c1r = C_re[HN + gid], c1i = C_im[HN + gid];
    float w0r = 2.0f*(c0r*db_re - c0i*db_im), w0i = 2.0f*(c0r*db_im + c0i*db_re);
    float w1r = 2.0f*(c1r*db_re - c1i*db_im), w1i = 2.0f*(c1r*db_im + c1i*db_re);
    W0r[n] = w0r; W0i[n] = w0i; W1r[n] = w1r; W1i[n] = w1i;
    P[gid]        = w0r;
    P[HN + gid]   = w0i;
    P[2*HN + gid] = w1r;
    P[3*HN + gid] = w1i;
    rT[gid*2]   = RRe[64][n];
    rT[gid*2+1] = RIm[64][n];
  }
  __syncthreads();
  if (tid < 128) {
    int d = tid & 63; bool c1 = tid >= 64;
    float s = 0.f;
    if (!c1) for (int n = 0; n < 64; ++n) s += W0r[n]*RRe[d][n] - W0i[n]*RIm[d][n];
    else     for (int n = 0; n < 64; ++n) s += W1r[n]*RRe[d][n] - W1i[n]*RIm[d][n];
    if (c1) K1[d] = s; else K0[d] = s;
  }
  __syncthreads();
  float dh = Dp[h];
  for (int idx = tid; idx < 4096; idx += 256) {
    int i = idx >> 6, j = idx & 63;
    float v = (i > j) ? K0[i-j] : (i < j ? K1[j-i-1] : (K0[0] + dh));
    Mc[(size_t)h*4096 + idx] = f2b_rne(v);
  }
  for (int idx = tid; idx < 256*64; idx += 256) {
    int row = idx >> 6, j = idx & 63;
    int n = (row >> 1) & 63;
    bool im = row & 1, bwd = row >= 128;
    int d = bwd ? j : 63-j;
    Vc[(size_t)h*16384 + idx] = f2b_rne(im ? RIm[d][n] : RRe[d][n]);
  }
  for (int idx = tid; idx < 64*256; idx += 256) {
    int i = idx >> 8, col = idx & 255;
    int n = (col >> 1) & 63;
    bool im = col & 1, bwd = col >= 128;
    int d = bwd ? 63-i : i+1;
    Uc[(size_t)h*16384 + idx] = f2b_rne(im ? -RIm[d][n] : RRe[d][n]);
  }
}

// ---------------- lnz v2: float4 x loads; one-pass LN -> zb + xt (bf16) ----------------
__global__ __launch_bounds__(256) void lnz_kernel(
    const float* __restrict__ x, const float* __restrict__ tt,
    const float* __restrict__ ln_g, const float* __restrict__ ln_b,
    ushort* __restrict__ zb, ushort* __restrict__ xt) {
  int b  = blockIdx.x >> 6;
  int l0 = (blockIdx.x & 63) * 32;
  int tid = threadIdx.x;
  int r8 = tid >> 3;        // 0..31 (h row within iter)
  int c  = tid & 7;         // 0..7  (l group of 4)
  __shared__ ushort XS[256][36];
  __shared__ float SS[32][33], SS2[32][33];
  __shared__ float MU[32], RS[32];
  float s[4] = {0.f,0.f,0.f,0.f}, s2[4] = {0.f,0.f,0.f,0.f};
  #pragma unroll
  for (int it = 0; it < 8; ++it) {
    int h = it*32 + r8;
    float ttv = tt[b*HH + h];
    float vv[4];
    *reinterpret_cast<float4*>(vv) =
        *reinterpret_cast<const float4*>(x + (size_t)(b*HH + h)*LL + l0 + c*4);
    #pragma unroll
    for (int j = 0; j < 4; ++j) {
      float w = vv[j] + ttv;
      s[j] += w; s2[j] = fmaf(w, w, s2[j]);
      XS[h][c*4 + j] = f2b_rne(w);
    }
  }
  #pragma unroll
  for (int j = 0; j < 4; ++j) { SS[c*4+j][r8] = s[j]; SS2[c*4+j][r8] = s2[j]; }
  __syncthreads();
  if (tid < 32) {
    float a = 0.f, a2 = 0.f;
    #pragma unroll
    for (int p = 0; p < 32; ++p) { a += SS[tid][p]; a2 += SS2[tid][p]; }
    float m = a * (1.0f/HH);
    float var = a2 * (1.0f/HH) - m*m;
    MU[tid] = m;
    RS[tid] = 1.0f / sqrtf(var + 1e-5f);
  }
  __syncthreads();
  #pragma unroll
  for (int it = 0; it < 8; ++it) {
    int h = it*32 + r8;
    float gg = ln_g[h], bb2 = ln_b[h];
    uint2 u2 = *reinterpret_cast<const uint2*>(&XS[h][c*4]);
    float v0, v1, v2, v3;
    UNPK(u2.x, v0, v1); UNPK(u2.y, v2, v3);
    int l = c*4;
    float z0 = (v0 - MU[l])   * RS[l]   * gg + bb2;
    float z1 = (v1 - MU[l+1]) * RS[l+1] * gg + bb2;
    float z2 = (v2 - MU[l+2]) * RS[l+2] * gg + bb2;
    float z3 = (v3 - MU[l+3]) * RS[l+3] * gg + bb2;
    uint2 zo;
    zo.x = (uint)f2b_rne(z0) | ((uint)f2b_rne(z1) << 16);
    zo.y = (uint)f2b_rne(z2) | ((uint)f2b_rne(z3) << 16);
    size_t off = (size_t)(b*HH + h)*LL + l0 + l;
    *reinterpret_cast<uint2*>(zb + off) = zo;
    *reinterpret_cast<uint2*>(xt + off) = u2;
  }
}

// ---------------- ssm_all v2: split over b (4 b's per block) -> 2 blocks/CU ------------
// grid (2, HH); G slice [128][260] = 65 KB
__global__ __launch_bounds__(512) void ssm_all(
    const ushort* __restrict__ zb, const ushort* __restrict__ Vc,
    const ushort* __restrict__ Mc, const ushort* __restrict__ Uc,
    const float* __restrict__ P, const float* __restrict__ rT,
    ushort* __restrict__ g) {
  int b0 = blockIdx.x * 4;
  int h  = blockIdx.y;
  int tid = threadIdx.x, wid = tid >> 6, lane = tid & 63;
  int row16 = lane & 15, kg = lane >> 4;
  __shared__ ushort G[128][260];   // 65 KB: G[bc][comp] for 4 b's, overwritten by U

  // ---- phase 1: G = Vc_h @ Z (8 tiles of 64x64 over 8 waves) ----
  {
    int comp0 = (wid >> 1)*64, bct = (wid & 1)*64;
    f32x4v acc[4][4];
    #pragma unroll
    for (int fm = 0; fm < 4; ++fm)
      #pragma unroll
      for (int fn = 0; fn < 4; ++fn) acc[fm][fn] = (f32x4v){0.f,0.f,0.f,0.f};
    #pragma unroll
    for (int k0 = 0; k0 < 64; k0 += 32) {
      bf16x8v a[4], bv[4];
      #pragma unroll
      for (int fm = 0; fm < 4; ++fm)
        a[fm] = *reinterpret_cast<const bf16x8v*>(
            Vc + (size_t)h*16384 + (comp0 + fm*16 + row16)*64 + k0 + kg*8);
      #pragma unroll
      for (int fn = 0; fn < 4; ++fn) {
        int bc = bct + fn*16 + row16; int b = b0 + (bc >> 5), c = bc & 31;
        bv[fn] = *reinterpret_cast<const bf16x8v*>(
            zb + ((size_t)(b*HH + h))*LL + c*64 + k0 + kg*8);
      }
      #pragma unroll
      for (int fm = 0; fm < 4; ++fm)
        #pragma unroll
        for (int fn = 0; fn < 4; ++fn)
          acc[fm][fn] = __builtin_amdgcn_mfma_f32_16x16x32_bf16(a[fm], bv[fn], acc[fm][fn], 0,0,0);
    }
    #pragma unroll
    for (int fm = 0; fm < 4; ++fm)
      #pragma unroll
      for (int fn = 0; fn < 4; ++fn) {
        int bc = bct + fn*16 + row16;
        int comp = comp0 + fm*16 + kg*4;
        union { ushort us[4]; uint2 u2; } pk;
        #pragma unroll
        for (int r = 0; r < 4; ++r) pk.us[r] = f2b_rne(acc[fm][fn][r]);
        *reinterpret_cast<uint2*>(&G[bc][comp]) = pk.u2;
      }
  }
  __syncthreads();

  // ---- phase 2: 8 scan units (4 b x 2 dir) over 8 waves; U overwrites G in place ----
  {
    int bloc = wid & 3, dir = wid >> 2;
    int n = lane;
    float w_re = dir ? P[2*HN + h*64+n] : P[h*64+n];
    float w_im = dir ? P[3*HN + h*64+n] : P[HN + h*64+n];
    float rtr = rT[(h*64+n)*2], rti = rT[(h*64+n)*2+1];
    float sre = 0.f, sim = 0.f;
    if (dir == 0) {
      for (int c = 0; c < 32; ++c) {
        uint* slot = reinterpret_cast<uint*>(&G[bloc*32 + c][2*n]);
        uint gg = *slot;
        float ure = w_re*sre - w_im*sim;
        float uim = w_re*sim + w_im*sre;
        *slot = (uint)f2b_rne(ure) | ((uint)f2b_rne(uim) << 16);
        float gre, gim; UNPK(gg, gre, gim);
        float nre = rtr*sre - rti*sim + gre;
        float nim = rtr*sim + rti*sre + gim;
        sre = nre; sim = nim;
      }
    } else {
      for (int c = 31; c >= 0; --c) {
        uint* slot = reinterpret_cast<uint*>(&G[bloc*32 + c][128 + 2*n]);
        uint gg = *slot;
        float ure = w_re*sre - w_im*sim;
        float uim = w_re*sim + w_im*sre;
        *slot = (uint)f2b_rne(ure) | ((uint)f2b_rne(uim) << 16);
        float gre, gim; UNPK(gg, gre, gim);
        float nre = rtr*sre - rti*sim + gre;
        float nim = rtr*sim + rti*sre + gim;
        sre = nre; sim = nim;
      }
    }
  }
  __syncthreads();

  // ---- phase 3: Y = Mc@Z + Uc@U, GELU -> g[b][h][l]; 8 tiles of 16i x 64bc ----
  {
    int i0 = (wid & 3)*16, bct = (wid >> 2)*64;
    f32x4v acc[4];
    #pragma unroll
    for (int fn = 0; fn < 4; ++fn) acc[fn] = (f32x4v){0.f,0.f,0.f,0.f};
    #pragma unroll
    for (int k0 = 0; k0 < 64; k0 += 32) {
      bf16x8v a = *reinterpret_cast<const bf16x8v*>(
          Mc + (size_t)h*4096 + (i0 + row16)*64 + k0 + kg*8);
      #pragma unroll
      for (int fn = 0; fn < 4; ++fn) {
        int bc = bct + fn*16 + row16; int b = b0 + (bc >> 5), c = bc & 31;
        bf16x8v bv = *reinterpret_cast<const bf16x8v*>(
            zb + ((size_t)(b*HH + h))*LL + c*64 + k0 + kg*8);
        acc[fn] = __builtin_amdgcn_mfma_f32_16x16x32_bf16(a, bv, acc[fn], 0,0,0);
      }
    }
    #pragma unroll
    for (int k0 = 0; k0 < 256; k0 += 32) {
      bf16x8v a = *reinterpret_cast<const bf16x8v*>(
          Uc + (size_t)h*16384 + (i0 + row16)*256 + k0 + kg*8);
      #pragma unroll
      for (int fn = 0; fn < 4; ++fn) {
        bf16x8v bv = *reinterpret_cast<const bf16x8v*>(&G[bct + fn*16 + row16][k0 + kg*8]);
        acc[fn] = __builtin_amdgcn_mfma_f32_16x16x32_bf16(a, bv, acc[fn], 0,0,0);
      }
    }
    #pragma unroll
    for (int fn = 0; fn < 4; ++fn) {
      int bc = bct + fn*16 + row16; int b = b0 + (bc >> 5), c = bc & 31;
      union { ushort us[4]; uint2 u2; } pk;
      #pragma unroll
      for (int r = 0; r < 4; ++r) {
        float v = acc[fn][r];
        float ge = 0.5f * v * (1.0f + erff(v * 0.70710678118654752f));
        pk.us[r] = f2b_rne(ge);
      }
      *reinterpret_cast<uint2*>(&g[((size_t)(b*HH + h))*LL + c*64 + i0 + kg*4]) = pk.u2;
    }
  }
}

// ---------------- fused_out v8b: R14 structure + nontemporal output stores -------------
__global__ __launch_bounds__(256, 2) void fused_out(
    const ushort* __restrict__ g, const ushort* __restrict__ Wob,
    const ushort* __restrict__ W1b, const ushort* __restrict__ W2b,
    const float* __restrict__ b_out, const float* __restrict__ b1v,
    const float* __restrict__ b2v, const ushort* __restrict__ xt,
    const float* __restrict__ tt,
    float* __restrict__ out1, float* __restrict__ out2) {
  int l0 = blockIdx.x * 32;
  int b  = blockIdx.y;
  int tid = threadIdx.x, wid = tid >> 6, lane = tid & 63;
  int row16 = lane & 15, kg = lane >> 4;
  int o0 = wid * 64;

  __shared__ ushort Tg[32][274];
  __shared__ ushort X[256][38];

  bf16x8v wA[8][4];
  #pragma unroll
  for (int k8 = 0; k8 < 8; ++k8)
    #pragma unroll
    for (int fo = 0; fo < 4; ++fo)
      wA[k8][fo] = *reinterpret_cast<const bf16x8v*>(
          Wob + (size_t)(o0 + fo*16 + row16)*HH + k8*32 + kg*8);

  {
    const ushort* gsrc = g + (size_t)b*HH*LL + l0;
    int cq = tid & 7;
    #pragma unroll
    for (int p = 0; p < 8; ++p) {
      int h = p*32 + (tid >> 3);
      uint2 v = *reinterpret_cast<const uint2*>(gsrc + (size_t)h*LL + cq*4);
      union { uint2 u2; ushort us[4]; } pk; pk.u2 = v;
      #pragma unroll
      for (int j = 0; j < 4; ++j) Tg[cq*4 + j][h] = pk.us[j];
    }
  }
  {
    const ushort* xsrc = xt + (size_t)b*HH*LL + l0;
    int cq = tid & 7;
    #pragma unroll
    for (int p = 0; p < 8; ++p) {
      int o = p*32 + (tid >> 3);
      uint2 v = *reinterpret_cast<const uint2*>(xsrc + (size_t)o*LL + cq*4);
      *reinterpret_cast<uint2*>(&X[o][cq*4]) = v;
    }
  }
  float biasA[4][4];
  #pragma unroll
  for (int fo = 0; fo < 4; ++fo)
    #pragma unroll
    for (int r = 0; r < 4; ++r)
      biasA[fo][r] = b_out[o0 + fo*16 + kg*4 + r];
  __syncthreads();

  f32x4v accA[4][2];
  #pragma unroll
  for (int fo = 0; fo < 4; ++fo)
    #pragma unroll
    for (int fl = 0; fl < 2; ++fl) accA[fo][fl] = (f32x4v){0.f,0.f,0.f,0.f};
  #pragma unroll
  for (int k8 = 0; k8 < 8; ++k8) {
    bf16x8v bb[2];
    #pragma unroll
    for (int fl = 0; fl < 2; ++fl)
      bb[fl] = *reinterpret_cast<const bf16x8v*>(&Tg[fl*16+row16][k8*32 + kg*8]);
    #pragma unroll
    for (int fo = 0; fo < 4; ++fo)
      #pragma unroll
      for (int fl = 0; fl < 2; ++fl)
        accA[fo][fl] = __builtin_amdgcn_mfma_f32_16x16x32_bf16(wA[k8][fo], bb[fl], accA[fo][fl], 0,0,0);
  }
  bf16x8v w1[8][4];
  #pragma unroll
  for (int k8 = 0; k8 < 8; ++k8)
    #pragma unroll
    for (int fo = 0; fo < 4; ++fo)
      w1[k8][fo] = *reinterpret_cast<const bf16x8v*>(
          W1b + (size_t)(o0 + fo*16 + row16)*HH + k8*32 + kg*8);
  uint2 gw[4][2];
  #pragma unroll
  for (int fo = 0; fo < 4; ++fo)
    #pragma unroll
    for (int fl = 0; fl < 2; ++fl) {
      union { ushort us[4]; uint2 u2; } pk;
      #pragma unroll
      for (int r = 0; r < 4; ++r) {
        int o = o0 + fo*16 + kg*4 + r;
        int l = fl*16 + row16;
        float v = accA[fo][fl][r] + biasA[fo][r] + b2f(X[o][l]);
        float gate = tanhf(v) * (1.0f/(1.0f + expf(-v)));
        pk.us[r] = f2b_rne(gate);
      }
      gw[fo][fl] = pk.u2;
    }
  __syncthreads();
  #pragma unroll
  for (int fo = 0; fo < 4; ++fo)
    #pragma unroll
    for (int fl = 0; fl < 2; ++fl)
      *reinterpret_cast<uint2*>(&Tg[fl*16+row16][o0 + fo*16 + kg*4]) = gw[fo][fl];
  __syncthreads();

  {
    f32x4v p[2][4];
    #pragma unroll
    for (int fl = 0; fl < 2; ++fl)
      #pragma unroll
      for (int fo = 0; fo < 4; ++fo) p[fl][fo] = (f32x4v){0.f,0.f,0.f,0.f};
    #pragma unroll
    for (int k8 = 0; k8 < 8; ++k8) {
      bf16x8v bb[2];
      #pragma unroll
      for (int fl = 0; fl < 2; ++fl)
        bb[fl] = *reinterpret_cast<const bf16x8v*>(&Tg[fl*16+row16][k8*32 + kg*8]);
      #pragma unroll
      for (int fl = 0; fl < 2; ++fl)
        #pragma unroll
        for (int fo = 0; fo < 4; ++fo)
          p[fl][fo] = __builtin_amdgcn_mfma_f32_16x16x32_bf16(bb[fl], w1[k8][fo], p[fl][fo], 0,0,0);
    }
    #pragma unroll
    for (int k8 = 0; k8 < 8; ++k8)
      #pragma unroll
      for (int fo = 0; fo < 4; ++fo)
        wA[k8][fo] = *reinterpret_cast<const bf16x8v*>(
            W2b + (size_t)(o0 + fo*16 + row16)*HH + k8*32 + kg*8);
    #pragma unroll
    for (int fl = 0; fl < 2; ++fl)
      #pragma unroll
      for (int fo = 0; fo < 4; ++fo) {
        int o  = o0 + fo*16 + row16;
        int lb = fl*16 + kg*4;
        float bias = b1v[o] - tt[b*HH + o];
        uint2 xv = *reinterpret_cast<const uint2*>(&X[o][lb]);
        float x0, x1, x2, x3;
        UNPK(xv.x, x0, x1); UNPK(xv.y, x2, x3);
        f32x4v v;
        v[0] = p[fl][fo][0] + bias + x0;
        v[1] = p[fl][fo][1] + bias + x1;
        v[2] = p[fl][fo][2] + bias + x2;
        v[3] = p[fl][fo][3] + bias + x3;
        __builtin_nontemporal_store(v,
            reinterpret_cast<f32x4v*>(&out1[((size_t)(b*HH + o))*LL + l0 + lb]));
      }
  }
  {
    f32x4v q[2][4];
    #pragma unroll
    for (int fl = 0; fl < 2; ++fl)
      #pragma unroll
      for (int fo = 0; fo < 4; ++fo) q[fl][fo] = (f32x4v){0.f,0.f,0.f,0.f};
    #pragma unroll
    for (int k8 = 0; k8 < 8; ++k8) {
      bf16x8v bb[2];
      #pragma unroll
      for (int fl = 0; fl < 2; ++fl)
        bb[fl] = *reinterpret_cast<const bf16x8v*>(&Tg[fl*16+row16][k8*32 + kg*8]);
      #pragma unroll
      for (int fl = 0; fl < 2; ++fl)
        #pragma unroll
        for (int fo = 0; fo < 4; ++fo)
          q[fl][fo] = __builtin_amdgcn_mfma_f32_16x16x32_bf16(bb[fl], wA[k8][fo], q[fl][fo], 0,0,0);
    }
    #pragma unroll
    for (int fl = 0; fl < 2; ++fl)
      #pragma unroll
      for (int fo = 0; fo < 4; ++fo) {
        int o  = o0 + fo*16 + row16;
        int lb = fl*16 + kg*4;
        float bias = b2v[o];
        f32x4v v;
        v[0] = q[fl][fo][0] + bias;
        v[1] = q[fl][fo][1] + bias;
        v[2] = q[fl][fo][2] + bias;
        v[3] = q[fl][fo][3] + bias;
        __builtin_nontemporal_store(v,
            reinterpret_cast<f32x4v*>(&out2[((size_t)(b*HH + o))*LL + l0 + lb]));
      }
  }
}

extern "C" void kernel_launch(void* const* d_in, const int* in_sizes, int n_in,
                              void* d_out, int out_size, void* d_ws, size_t ws_size,
                              hipStream_t stream) {
  const float* x    = (const float*)d_in[0];
  const float* t    = (const float*)d_in[1];
  const float* W_t  = (const float*)d_in[2];
  const float* b_t  = (const float*)d_in[3];
  const float* ln_g = (const float*)d_in[4];
  const float* ln_b = (const float*)d_in[5];
  const float* log_dt = (const float*)d_in[6];
  const float* log_A_real = (const float*)d_in[7];
  const float* A_imag = (const float*)d_in[8];
  const float* B_re = (const float*)d_in[9];
  const float* B_im = (const float*)d_in[10];
  const float* C_re = (const float*)d_in[11];
  const float* C_im = (const float*)d_in[12];
  const float* Dp   = (const float*)d_in[13];
  const float* W_out= (const float*)d_in[14];
  const float* b_out= (const float*)d_in[15];
  const float* W1   = (const float*)d_in[16];
  const float* b1   = (const float*)d_in[17];
  const float* W2   = (const float*)d_in[18];
  const float* b2   = (const float*)d_in[19];

  float* out1 = (float*)d_out;
  float* out2 = out1 + ELEMS;

  // ws: P(4HN) | tt | rT(2HN) | zb | Mc | Vc | Uc | g | Wob | W1b | W2b | xt
  float* P    = (float*)d_ws;
  float* tt   = P + 4*HN;
  float* rT   = tt + BB*HH;
  ushort* zb  = (ushort*)(rT + 2*HN);
  ushort* Mc  = zb + ELEMS;
  ushort* Vc  = Mc + (size_t)4096*HH;
  ushort* Uc  = Vc + (size_t)16384*HH;
  ushort* g   = Uc + (size_t)16384*HH;
  ushort* Wob = g + ELEMS;
  ushort* W1b = Wob + HH*HH;
  ushort* W2b = W1b + HH*HH;
  ushort* xt  = W2b + HH*HH;

  init_kernel<<<BB + 192 + HH, 256, 0, stream>>>(
      t, W_t, b_t, log_dt, log_A_real, A_imag, B_re, B_im, C_re, C_im, Dp,
      W_out, W1, W2, P, tt, Wob, W1b, W2b, Mc, Vc, Uc, rT);
  lnz_kernel<<<BB*64, 256, 0, stream>>>(x, tt, ln_g, ln_b, zb, xt);
  ssm_all<<<dim3(2, HH), 512, 0, stream>>>(zb, Vc, Mc, Uc, P, rT, g);
  fused_out<<<dim3(LL/32, BB), 256, 0, stream>>>(g, Wob, W1b, W2b, b_out, b1, b2,
                                                 xt, tt, out1, out2);
}